// Round 8
// baseline (1491.132 us; speedup 1.0000x reference)
//
#include <hip/hip_runtime.h>
#include <hip/hip_fp16.h>
#include <hip/hip_cooperative_groups.h>
#include <math.h>

namespace cg = cooperative_groups;

#define Bn 32
#define Tn 64
#define Fdim 32
#define Gdim 32
#define Hdim 256
#define Ndim 20000
#define Cdim 32
#define G4 1024      // 4*H
#define BT 2048      // B*T
#define EPSc 1e-5f

// workspace layout (float offsets) — unchanged from the multi-kernel version
#define S_GAT   0u                       // 64
#define S_BN    64u                      // 4*512
#define TABLE   2112u                    // 40000 ints
#define WIHP    42112u                   // 8 slots x 131072 uints (Wih^T f16)
#define PSLOT   131072u
#define WHHP    (WIHP + 8*PSLOT)         // 8 slots x 131072 uints (Whh f16)
#define LSTM_INH (WHHP + 8*PSLOT)        // BT*32 uints
#define XPOFF   (LSTM_INH + 65536)       // 3 x 2,097,152 fp32
#define BUF0H   (XPOFF + 3*2097152)      // BT*128 uints
#define BUF1    (BUF0H + 262144)         // BT*256 fp32
#define BUFNH   (BUF1 + 524288)          // BT*128 uints
#define HB0H    (BUFNH + 262144)         // 3 x BT*128 uints
#define HB1     (HB0H + 3*262144)        // 3 x BT*256 fp32

#define GTHREADS 262144                  // 256 blocks * 1024 threads

__device__ __forceinline__ float sigmoidf_(float x){ return 1.0f/(1.0f + __expf(-x)); }
__device__ __forceinline__ float tanhf_(float x){ return 2.0f/(1.0f+__expf(-2.0f*x)) - 1.0f; }

typedef _Float16 h2t __attribute__((ext_vector_type(2)));

__device__ __forceinline__ float fdot2_(unsigned w, unsigned h, float acc){
#if defined(__has_builtin) && __has_builtin(__builtin_amdgcn_fdot2)
  return __builtin_amdgcn_fdot2(__builtin_bit_cast(h2t, w), __builtin_bit_cast(h2t, h), acc, false);
#else
  h2t a = __builtin_bit_cast(h2t, w), b = __builtin_bit_cast(h2t, h);
  acc = fmaf((float)a.x, (float)b.x, acc);
  return fmaf((float)a.y, (float)b.y, acc);
#endif
}

__device__ __forceinline__ unsigned packh_(float lo, float hi){
  unsigned ulo = (unsigned)__half_as_ushort(__float2half(lo));
  unsigned uhi = (unsigned)__half_as_ushort(__float2half(hi));
  return ulo | (uhi << 16);
}

// ---- input projection (proj_kernel body, virtual-block form) ------------
// v in [0,1024): mtile = v&255 (8 rows), nblk = v>>8 (256 cols)
__device__ __forceinline__ void proj_dev(const unsigned* __restrict__ x,
    const unsigned* __restrict__ wt, const float* __restrict__ bias,
    float* __restrict__ outp, int K2, int v, int lane){
  int mtile = v & 255, nblk = v >> 8;
  int n = nblk*256 + lane;
  int m0 = mtile*8;
  const unsigned* xh = x + (size_t)m0*K2;
  float bv = bias[n];
  float acc[8];
  #pragma unroll
  for (int i=0;i<8;i++) acc[i]=bv;
  for (int k2=0;k2<K2;k2+=4){
    unsigned w0 = wt[(size_t)(k2+0)*G4+n];
    unsigned w1 = wt[(size_t)(k2+1)*G4+n];
    unsigned w2 = wt[(size_t)(k2+2)*G4+n];
    unsigned w3 = wt[(size_t)(k2+3)*G4+n];
    #pragma unroll
    for (int i=0;i<8;i++){
      uint4 xv = *(const uint4*)(xh + i*K2 + k2);
      acc[i]=fdot2_(w0,xv.x,acc[i]); acc[i]=fdot2_(w1,xv.y,acc[i]);
      acc[i]=fdot2_(w2,xv.z,acc[i]); acc[i]=fdot2_(w3,xv.w,acc[i]);
    }
  }
  float* op = outp + (size_t)m0*G4 + n;
  #pragma unroll
  for (int i=0;i<8;i++) op[i*G4]=acc[i];
}

// ---- LSTM recurrence (v2 body verbatim; proven 120.5 us/dispatch) -------
__device__ __forceinline__ void rec_dev(float* lds, const float* __restrict__ xp,
    const unsigned* __restrict__ wt, float* __restrict__ out,
    unsigned* __restrict__ outh, int tid){
  unsigned* lw   = (unsigned*)lds;           // 32768 uints (128 KB) weights
  float*    part = lds + 32768;              // 4096 floats (16 KB) partials
  unsigned* hp   = (unsigned*)(lds + 36864); // 2 x 128 uints h packed pairs
  int j = tid & 255, kq = tid >> 8;

  unsigned w[96];
  #pragma unroll
  for (int c=0;c<4;c++){
    #pragma unroll
    for (int i=0;i<6;i++){
      uint4 v = *(const uint4*)(wt + ((c*8+i)*1024 + tid)*4);
      w[(c*6+i)*4+0]=v.x; w[(c*6+i)*4+1]=v.y; w[(c*6+i)*4+2]=v.z; w[(c*6+i)*4+3]=v.w;
    }
    #pragma unroll
    for (int i=6;i<8;i++){
      uint4 v = *(const uint4*)(wt + ((c*8+i)*1024 + tid)*4);
      *(uint4*)(lw + ((c*2+(i-6))*1024 + tid)*4) = v;
    }
  }
  float cst = 0.0f;
  if (tid < 128){ hp[tid] = 0u; hp[128+tid] = 0u; }
  __syncthreads();

  int p = 0;
  for (int t=0; t<Tn; t++){
    float ac0, ac1, ac2, ac3;
    if (kq == 0){
      float4 xv = *(const float4*)(xp + t*G4 + 4*j);
      ac0=xv.x; ac1=xv.y; ac2=xv.z; ac3=xv.w;
    } else { ac0=0.f; ac1=0.f; ac2=0.f; ac3=0.f; }
    const unsigned* hrow = hp + p*128 + kq*32;
    #pragma unroll
    for (int ic=0; ic<6; ic++){
      uint4 hv = *(const uint4*)(hrow + 4*ic);
      ac0=fdot2_(w[0*24+ic*4+0],hv.x,ac0); ac0=fdot2_(w[0*24+ic*4+1],hv.y,ac0);
      ac0=fdot2_(w[0*24+ic*4+2],hv.z,ac0); ac0=fdot2_(w[0*24+ic*4+3],hv.w,ac0);
      ac1=fdot2_(w[1*24+ic*4+0],hv.x,ac1); ac1=fdot2_(w[1*24+ic*4+1],hv.y,ac1);
      ac1=fdot2_(w[1*24+ic*4+2],hv.z,ac1); ac1=fdot2_(w[1*24+ic*4+3],hv.w,ac1);
      ac2=fdot2_(w[2*24+ic*4+0],hv.x,ac2); ac2=fdot2_(w[2*24+ic*4+1],hv.y,ac2);
      ac2=fdot2_(w[2*24+ic*4+2],hv.z,ac2); ac2=fdot2_(w[2*24+ic*4+3],hv.w,ac2);
      ac3=fdot2_(w[3*24+ic*4+0],hv.x,ac3); ac3=fdot2_(w[3*24+ic*4+1],hv.y,ac3);
      ac3=fdot2_(w[3*24+ic*4+2],hv.z,ac3); ac3=fdot2_(w[3*24+ic*4+3],hv.w,ac3);
    }
    #pragma unroll
    for (int ic=6; ic<8; ic++){
      uint4 hv = *(const uint4*)(hrow + 4*ic);
      { uint4 lv = *(const uint4*)(lw + ((0*2+(ic-6))*1024 + tid)*4);
        ac0=fdot2_(lv.x,hv.x,ac0); ac0=fdot2_(lv.y,hv.y,ac0);
        ac0=fdot2_(lv.z,hv.z,ac0); ac0=fdot2_(lv.w,hv.w,ac0); }
      { uint4 lv = *(const uint4*)(lw + ((1*2+(ic-6))*1024 + tid)*4);
        ac1=fdot2_(lv.x,hv.x,ac1); ac1=fdot2_(lv.y,hv.y,ac1);
        ac1=fdot2_(lv.z,hv.z,ac1); ac1=fdot2_(lv.w,hv.w,ac1); }
      { uint4 lv = *(const uint4*)(lw + ((2*2+(ic-6))*1024 + tid)*4);
        ac2=fdot2_(lv.x,hv.x,ac2); ac2=fdot2_(lv.y,hv.y,ac2);
        ac2=fdot2_(lv.z,hv.z,ac2); ac2=fdot2_(lv.w,hv.w,ac2); }
      { uint4 lv = *(const uint4*)(lw + ((3*2+(ic-6))*1024 + tid)*4);
        ac3=fdot2_(lv.x,hv.x,ac3); ac3=fdot2_(lv.y,hv.y,ac3);
        ac3=fdot2_(lv.z,hv.z,ac3); ac3=fdot2_(lv.w,hv.w,ac3); }
    }
    *(float4*)(part + kq*1024 + 4*j) = make_float4(ac0,ac1,ac2,ac3);
    __syncthreads();
    if (tid < 256){
      int u = tid;
      float gi = part[u]     + part[1024+u]     + part[2048+u]     + part[3072+u];
      float gf = part[256+u] + part[1024+256+u] + part[2048+256+u] + part[3072+256+u];
      float gg = part[512+u] + part[1024+512+u] + part[2048+512+u] + part[3072+512+u];
      float go = part[768+u] + part[1024+768+u] + part[2048+768+u] + part[3072+768+u];
      cst = sigmoidf_(gf)*cst + sigmoidf_(gi)*tanhf_(gg);
      float h = sigmoidf_(go)*tanhf_(cst);
      out[t*Hdim + u] = h;
      float hpartner = __shfl_xor(h, 1);
      if ((u & 1) == 0){
        unsigned hh = packh_(h, hpartner);
        hp[(p^1)*128 + (u>>1)] = hh;
        outh[t*128 + (u>>1)] = hh;
      }
    }
    __syncthreads();
    p ^= 1;
  }
}

struct MegaArgs {
  const float *feats, *gat;
  const int *row_ids, *node_ids;
  const float *sWih0, *sWhh0, *sb0, *sWih1, *sWhh1, *sb1;
  const float *hWih, *hWhh, *hb;
  const float *bng, *bnb, *bsg, *bsb, *hbg, *hbb;
  const float *actW, *actB, *tW, *tB, *rW, *rB;
  float* ws; float* out;
};

__global__ __launch_bounds__(1024,1) void mega_kernel(MegaArgs a){
  extern __shared__ float lds[];
  cg::grid_group grd = cg::this_grid();
  const int tid = threadIdx.x;
  const int bid = blockIdx.x;
  const int gid = bid*1024 + tid;
  float* ws = a.ws;
  int* table = (int*)(ws + TABLE);
  unsigned* wih = (unsigned*)(ws + WIHP);
  unsigned* whh = (unsigned*)(ws + WHHP);

  // ---- P0: init stats + table ----
  if (gid < 2112) ws[gid] = 0.0f;
  for (int i = gid; i < 40000; i += GTHREADS) table[i] = 0x7fffffff;
  grd.sync();

  // ---- P1: node table fill + gat mean/var partials ----
  if (gid < Ndim) atomicMin(&table[a.node_ids[gid]], gid);
  {
    float* ss = lds; float* sq = lds + 1024;
    const int total = Bn*Ndim*Gdim;
    float s=0.f,q=0.f;
    for (int i = gid; i < total; i += GTHREADS){ float v = a.gat[i]; s+=v; q+=v*v; }
    ss[tid]=s; sq[tid]=q; __syncthreads();
    for (int off=512; off>=32; off>>=1){
      if (tid<off){ ss[tid]+=ss[tid+off]; sq[tid]+=sq[tid+off]; }
      __syncthreads();
    }
    if (tid<32){ atomicAdd(&ws[S_GAT+tid], ss[tid]); atomicAdd(&ws[S_GAT+32+tid], sq[tid]); }
  }
  grd.sync();

  // ---- P2: build lstm_in + pack Wih + pack Whh ----
  {
    const float* sums = ws + S_GAT;
    unsigned* outp = (unsigned*)(ws + LSTM_INH);
    for (int gt = gid; gt < BT*32; gt += GTHREADS){
      int pos = gt >> 5; int k2 = gt & 31;
      float lo, hi;
      if (k2 < 16){
        float2 v = *(const float2*)(a.feats + pos*Fdim + 2*k2);
        lo = v.x; hi = v.y;
      } else {
        int g0 = 2*(k2-16);
        int r = a.row_ids[pos];
        int idx = table[r];
        if (idx < Ndim){
          int b = pos / Tn;
          float2 x = *(const float2*)(a.gat + (size_t)(b*Ndim + idx)*Gdim + g0);
          const float cnt = (float)(Bn*Ndim);
          float m0 = sums[g0]/cnt,   v0 = sums[32+g0]/cnt - m0*m0;
          float m1 = sums[g0+1]/cnt, v1 = sums[32+g0+1]/cnt - m1*m1;
          lo = (x.x-m0)*a.bng[g0]*rsqrtf(v0+EPSc) + a.bnb[g0];
          hi = (x.y-m1)*a.bng[g0+1]*rsqrtf(v1+EPSc) + a.bnb[g0+1];
        } else { lo = 0.0f; hi = 0.0f; }
      }
      outp[gt] = packh_(lo, hi);
    }
    // Wih pack+transpose (elementwise): slot0 K=64 (32768 dwords), slots1-7 K=256
    for (int f = gid; f < 950272; f += GTHREADS){
      int mat, idx;
      if (f < 32768){ mat = 0; idx = f; }
      else { int r = f - 32768; mat = 1 + (r >> 17); idx = r & 131071; }
      int K = (mat==0) ? 64 : 256;
      int k2 = idx >> 10, n = idx & 1023;
      const float* src = (mat==0) ? a.sWih0 : (mat==1) ? a.sWih1
                         : a.hWih + (size_t)(mat-2)*G4*Hdim;
      const float* p = src + (size_t)n*K + 2*k2;
      wih[(size_t)mat*PSLOT + (size_t)k2*G4 + n] = packh_(p[0], p[1]);
    }
    // Whh pack (elementwise, v2 layout)
    for (int g2 = gid; g2 < 1048576; g2 += GTHREADS){
      int m = g2 >> 17;
      int rem = g2 & 0x1FFFF;
      int q = rem & 3;
      int t2 = (rem >> 2) & 1023;
      int ci = rem >> 12;
      int c = ci >> 3, i = ci & 7;
      int j = t2 & 255, kq = t2 >> 8;
      int r = 4*j + c;
      int k = kq*64 + 8*i + 2*q;
      const float* W = (m==0) ? a.sWhh0 : (m==1) ? a.sWhh1
                       : a.hWhh + (size_t)(m-2)*G4*Hdim;
      whh[g2] = packh_(W[r*256 + k], W[r*256 + k + 1]);
    }
  }
  grd.sync();

  // ---- P3: proj shared L0 (K2=32) ----
  { int v = bid*4 + (tid>>8), lane = tid & 255;
    proj_dev((const unsigned*)(ws+LSTM_INH), wih, a.sb0, ws+XPOFF, 32, v, lane); }
  grd.sync();

  // ---- P4: rec shared L0 ----
  if (bid < 32)
    rec_dev(lds, ws+XPOFF + (size_t)bid*Tn*G4, whh,
            ws+BUF1 + (size_t)bid*Tn*Hdim,
            (unsigned*)(ws+BUF0H) + (size_t)bid*Tn*128, tid);
  grd.sync();

  // ---- P5: proj shared L1 (K2=128) ----
  { int v = bid*4 + (tid>>8), lane = tid & 255;
    proj_dev((const unsigned*)(ws+BUF0H), wih + PSLOT, a.sb1, ws+XPOFF, 128, v, lane); }
  grd.sync();

  // ---- P6: rec shared L1 ----
  if (bid < 32)
    rec_dev(lds, ws+XPOFF + (size_t)bid*Tn*G4, whh + PSLOT,
            ws+BUF1 + (size_t)bid*Tn*Hdim,
            (unsigned*)(ws+BUF0H) + (size_t)bid*Tn*128, tid);
  grd.sync();

  // ---- P7: shared batchnorm stats ----
  { int vb = bid*4 + (tid>>8), lane = tid & 255;
    if (vb < 8){
      const float* in = ws+BUF1 + (size_t)vb*256*Hdim;
      float s=0.f,q=0.f;
      for (int r2=0;r2<256;r2++){ float v = in[r2*Hdim + lane]; s+=v; q+=v*v; }
      atomicAdd(&ws[S_BN+lane], s);
      atomicAdd(&ws[S_BN+Hdim+lane], q);
    } }
  grd.sync();

  // ---- P8: normalize -> BUFNH (BT*128 == GTHREADS exactly) ----
  { const float* stats = ws + S_BN;
    int i2 = gid;
    int h2 = i2 & 127; int m2 = i2 >> 7;
    int h0 = 2*h2;
    float2 v = *(const float2*)(ws+BUF1 + (size_t)m2*Hdim + h0);
    float m0 = stats[h0]*(1.0f/BT),   v0 = stats[Hdim+h0]*(1.0f/BT) - m0*m0;
    float m1 = stats[h0+1]*(1.0f/BT), v1 = stats[Hdim+h0+1]*(1.0f/BT) - m1*m1;
    float lo = (v.x-m0)*a.bsg[h0]*rsqrtf(v0+EPSc) + a.bsb[h0];
    float hi = (v.y-m1)*a.bsg[h0+1]*rsqrtf(v1+EPSc) + a.bsb[h0+1];
    ((unsigned*)(ws+BUFNH))[i2] = packh_(lo, hi); }
  grd.sync();

  // ---- P9: proj heads L0 ----
  for (int hd=0; hd<3; hd++){
    int v = bid*4 + (tid>>8), lane = tid & 255;
    proj_dev((const unsigned*)(ws+BUFNH), wih + (size_t)(2+hd*2)*PSLOT,
             a.hb + (size_t)(hd*2)*G4, ws+XPOFF + (size_t)hd*2097152, 128, v, lane);
  }
  grd.sync();

  // ---- P10: rec heads L0 ----
  if (bid < 96){
    int hd = bid >> 5, b = bid & 31;
    rec_dev(lds, ws+XPOFF + (size_t)hd*2097152 + (size_t)b*Tn*G4,
            whh + (size_t)(2+hd*2)*PSLOT,
            ws+HB1 + (size_t)hd*524288 + (size_t)b*Tn*Hdim,
            (unsigned*)(ws+HB0H) + (size_t)hd*262144 + (size_t)b*Tn*128, tid);
  }
  grd.sync();

  // ---- P11: proj heads L1 ----
  for (int hd=0; hd<3; hd++){
    int v = bid*4 + (tid>>8), lane = tid & 255;
    proj_dev((const unsigned*)(ws+HB0H) + (size_t)hd*262144,
             wih + (size_t)(2+hd*2+1)*PSLOT,
             a.hb + (size_t)(hd*2+1)*G4, ws+XPOFF + (size_t)hd*2097152, 128, v, lane);
  }
  grd.sync();

  // ---- P12: rec heads L1 ----
  if (bid < 96){
    int hd = bid >> 5, b = bid & 31;
    rec_dev(lds, ws+XPOFF + (size_t)hd*2097152 + (size_t)b*Tn*G4,
            whh + (size_t)(2+hd*2+1)*PSLOT,
            ws+HB1 + (size_t)hd*524288 + (size_t)b*Tn*Hdim,
            (unsigned*)(ws+HB0H) + (size_t)hd*262144 + (size_t)b*Tn*128, tid);
  }
  grd.sync();

  // ---- P13: heads batchnorm stats ----
  { int vb = bid*4 + (tid>>8), lane = tid & 255;
    if (vb < 24){
      int hd = vb >> 3, blk = vb & 7;
      const float* in = ws+HB1 + (size_t)hd*524288 + (size_t)blk*256*Hdim;
      float* st = ws + S_BN + (size_t)(1+hd)*512;
      float s=0.f,q=0.f;
      for (int r2=0;r2<256;r2++){ float v = in[r2*Hdim + lane]; s+=v; q+=v*v; }
      atomicAdd(&st[lane], s);
      atomicAdd(&st[Hdim+lane], q);
    } }
  grd.sync();

  // ---- P14: final (block 0 only; 1024 threads) ----
  if (bid == 0){
    float* v0 = lds;            // 8192 floats
    float* lg = lds + 8192;     // 1024 floats
    const float* stats = ws + S_BN;
    const float* h0 = ws + HB1;
    const float* h1 = ws + HB1 + 524288;
    const float* h2 = ws + HB1 + 2*524288;
    float* outp = a.out;
    for (int i=tid; i<Bn*Hdim; i+=1024){
      int b=i>>8, h=i&255;
      float sm = stats[512 + h], sq = stats[512+256+h];
      float mean = sm*(1.0f/BT); float var = sq*(1.0f/BT) - mean*mean;
      v0[i] = (h0[(b*Tn+63)*Hdim + h] - mean)*a.hbg[h]*rsqrtf(var+EPSc) + a.hbb[h];
    }
    __syncthreads();
    { int i = tid;            // Bn*Cdim == 1024 exactly
      int b=i>>5, cc=i&31;
      float acc = a.actB[cc];
      const float* wrow = a.actW + cc*Hdim;
      const float* vrow = v0 + b*Hdim;
      #pragma unroll 4
      for (int h=0;h<Hdim;h++) acc = fmaf(vrow[h], wrow[h], acc);
      lg[i] = acc; }
    __syncthreads();
    if (tid < Bn){
      int b = tid;
      float m = -1e30f;
      #pragma unroll
      for (int cc=0; cc<Cdim; cc++) m = fmaxf(m, lg[b*Cdim+cc]);
      float e[Cdim]; float s = 0.f;
      #pragma unroll
      for (int cc=0; cc<Cdim; cc++){ float ee = __expf(lg[b*Cdim+cc]-m); e[cc]=ee; s+=ee; }
      float inv = 1.0f/s;
      #pragma unroll
      for (int cc=0; cc<Cdim; cc++) outp[b*Cdim+cc] = e[cc]*inv;
    }
    if (tid < 64){
      int b = tid & 31; int w = tid >> 5;
      const float* hh = w ? h2 : h1;
      const float* fw = w ? a.rW : a.tW;
      float fb = w ? a.rB[0] : a.tB[0];
      int hd = 1 + w;
      float acc = fb;
      for (int h=0; h<Hdim; h++){
        float sm = stats[(1+hd)*512 + h], sq = stats[(1+hd)*512+256+h];
        float mean = sm*(1.0f/BT); float var = sq*(1.0f/BT) - mean*mean;
        float v = (hh[(b*Tn+63)*Hdim + h] - mean)*a.hbg[hd*Hdim+h]*rsqrtf(var+EPSc) + a.hbb[hd*Hdim+h];
        acc = fmaf(v, fw[h], acc);
      }
      outp[1024 + w*32 + b] = acc;
    }
  }
}

extern "C" void kernel_launch(void* const* d_in, const int* in_sizes, int n_in,
                              void* d_out, int out_size, void* d_ws, size_t ws_size,
                              hipStream_t stream){
  MegaArgs ma;
  ma.feats   = (const float*)d_in[0];
  ma.gat     = (const float*)d_in[1];
  ma.row_ids = (const int*)d_in[2];
  ma.node_ids= (const int*)d_in[3];
  ma.sWih0   = (const float*)d_in[4];
  ma.sWhh0   = (const float*)d_in[5];
  ma.sb0     = (const float*)d_in[6];
  ma.sWih1   = (const float*)d_in[7];
  ma.sWhh1   = (const float*)d_in[8];
  ma.sb1     = (const float*)d_in[9];
  ma.hWih    = (const float*)d_in[10];
  ma.hWhh    = (const float*)d_in[11];
  ma.hb      = (const float*)d_in[12];
  ma.bng     = (const float*)d_in[13];
  ma.bnb     = (const float*)d_in[14];
  ma.bsg     = (const float*)d_in[15];
  ma.bsb     = (const float*)d_in[16];
  ma.hbg     = (const float*)d_in[17];
  ma.hbb     = (const float*)d_in[18];
  ma.actW    = (const float*)d_in[19];
  ma.actB    = (const float*)d_in[20];
  ma.tW      = (const float*)d_in[21];
  ma.tB      = (const float*)d_in[22];
  ma.rW      = (const float*)d_in[23];
  ma.rB      = (const float*)d_in[24];
  ma.ws      = (float*)d_ws;
  ma.out     = (float*)d_out;

  const int REC_LDS = 148480;   // rec phase: 128K lw + 16K part + 1K hp
  hipFuncSetAttribute((const void*)mega_kernel, hipFuncAttributeMaxDynamicSharedMemorySize, REC_LDS);

  void* params[] = { (void*)&ma };
  hipLaunchCooperativeKernel((const void*)mega_kernel, dim3(256), dim3(1024),
                             params, REC_LDS, stream);
}